// Round 4
// baseline (396.519 us; speedup 1.0000x reference)
//
#include <hip/hip_runtime.h>
#include <hip/hip_bf16.h>
#include <stdint.h>

#define HD 128
#define GD 64
#define OUTD 16
#define NR 16   // atomic privatization replicas
#define PCH 32  // pool chunks per graph

typedef unsigned short u16;
typedef __attribute__((ext_vector_type(8))) short short8;
typedef __attribute__((ext_vector_type(4))) float f32x4;
typedef __attribute__((ext_vector_type(4))) unsigned short u16x4;

__device__ __forceinline__ float bf2f(u16 u) {
  union { uint32_t i; float f; } v; v.i = ((uint32_t)u) << 16; return v.f;
}
__device__ __forceinline__ u16 f2bf(float f) {
  union { __hip_bfloat16 h; u16 u; } v; v.h = __float2bfloat16(f); return v.u;
}

// count pass: layout-detect + privatized per-col count + batch convert.
// Reads ONLY the col half of edge_index (and bt).  k = blockIdx & (NR-1);
// fill2_k MUST use the same edge->k mapping (same grid shape).
__global__ __launch_bounds__(256)
void count_k(const int* __restrict__ ei, const int* __restrict__ bt,
             int* __restrict__ b32, int* __restrict__ cntR, int E, int N) {
  __shared__ int s_is64;
  if (threadIdx.x == 0) {
    int all0 = 1;
    for (int k = 1; k < 128; k += 2) all0 &= (ei[k] == 0);
    s_is64 = all0;
  }
  __syncthreads();
  int is64 = s_is64;
  int i = blockIdx.x * 256 + threadIdx.x;
  if (i < E) {
    int c = is64 ? ei[2 * (E + i)] : ei[E + i];
    c = (c < 0) ? 0 : (c >= N ? N - 1 : c);
    int k = blockIdx.x & (NR - 1);
    atomicAdd(&cntR[k * N + c], 1);
  }
  if (i < N) {
    int v = is64 ? bt[2 * i] : bt[i];
    b32[i] = (v < 0) ? 0 : (v >= GD ? GD - 1 : v);
  }
}

// ---- scan; scan1 sums the NR replicas inline
__global__ void scan1_k(const int* __restrict__ cntR, int* __restrict__ offs,
                        int* __restrict__ bsum, int Np, int N) {
  __shared__ int s[1024];
  int i = blockIdx.x * 1024 + threadIdx.x;
  int v = 0;
  if (i < Np) {
#pragma unroll
    for (int k = 0; k < NR; ++k) v += cntR[k * N + i];
  }
  s[threadIdx.x] = v;
  __syncthreads();
  for (int off = 1; off < 1024; off <<= 1) {
    int t = (threadIdx.x >= off) ? s[threadIdx.x - off] : 0;
    __syncthreads();
    s[threadIdx.x] += t;
    __syncthreads();
  }
  if (i < Np) offs[i] = s[threadIdx.x] - v;
  if (threadIdx.x == 1023) bsum[blockIdx.x] = s[1023];
}

// fused: prefix the block sums (thread 0, <=49 adds), finalize offs,
// emit per-replica cursor bases, offs[N]=E
__global__ void scan3curs_k(int* __restrict__ offs, const int* __restrict__ bsum,
                            const int* __restrict__ cntR, int* __restrict__ cursR,
                            int Np, int E, int N, int nb1024) {
  __shared__ int s_pref;
  int n = blockIdx.x * 256 + threadIdx.x;
  if (threadIdx.x == 0) {
    int chunk = (blockIdx.x * 256) >> 10;   // all 256 nodes in a block share one
    int sum = 0;                            // 1024-chunk (256 | 1024)
    for (int i = 0; i < chunk; ++i) sum += bsum[i];
    s_pref = sum;
  }
  __syncthreads();
  if (n < Np) {
    int o = offs[n] + s_pref;
    offs[n] = o;
    int run = o;
#pragma unroll
    for (int k = 0; k < NR; ++k) { cursR[k * N + n] = run; run += cntR[k * N + n]; }
  }
  if (n == 0) offs[Np] = E;
}

// fill CSC directly from edge_index: p = atomicAdd(cursR[k][col]) (int atomic,
// L2-resident); csc[p] = {row, bits(|w|)}.  No eidx/rank intermediates.
__global__ __launch_bounds__(256)
void fill2_k(const int* __restrict__ ei, const float* __restrict__ ea,
             int* __restrict__ cursR, int2* __restrict__ csc, int E, int N) {
  __shared__ int s_is64;
  if (threadIdx.x == 0) {
    int all0 = 1;
    for (int k = 1; k < 128; k += 2) all0 &= (ei[k] == 0);
    s_is64 = all0;
  }
  __syncthreads();
  int is64 = s_is64;
  int e = blockIdx.x * 256 + threadIdx.x;
  if (e >= E) return;
  int r = is64 ? ei[2 * e] : ei[e];
  int c = is64 ? ei[2 * (E + e)] : ei[E + e];
  r = (r < 0) ? 0 : (r >= N ? N - 1 : r);
  c = (c < 0) ? 0 : (c >= N ? N - 1 : c);
  int k = blockIdx.x & (NR - 1);
  float a = ea[e];
  float w = isnan(a) ? 0.f : fabsf(a);
  int p = atomicAdd(&cursR[k * N + c], 1);
  csc[p] = make_int2(r, __float_as_int(w));
}

// merged: dinv[n] = rsqrt(sum of in-weights + 1)  AND
// transpose+convert all 3 weights: Wt[l][n][k] = bf16(W_l[k][n])
__global__ void deg_convw_k(const int* __restrict__ offs, const int2* __restrict__ csc,
                            float* __restrict__ dinv,
                            const float* __restrict__ W0, const float* __restrict__ W1,
                            const float* __restrict__ W2, u16* __restrict__ Wt, int N) {
  int i = blockIdx.x * 256 + threadIdx.x;
  if (i < 3 * HD * HD) {
    int l = i / (HD * HD);
    int r = i - l * (HD * HD);
    int n = r >> 7, k = r & 127;
    const float* W = (l == 0) ? W0 : (l == 1) ? W1 : W2;
    Wt[i] = f2bf(W[k * HD + n]);
  }
  if (i < N) {
    int p = offs[i], pe = offs[i + 1];
    float s = 0.f;
    for (; p < pe; ++p) s += __int_as_float(csc[p].y);
    dinv[i] = rsqrtf(s + 1.0f);
  }
}

// ---- shared MFMA core (operands swapped: mfma(W_frag, A_frag)).
// Lane owns x-row arow (col index = lane&15 of second operand) and 4
// consecutive output columns n = c*16 + qd*4 + r  (row index of first
// operand = (lane>>4)*4 + reg).  Epilogue: one dinv scalar, 8B packed stores.
__device__ __forceinline__ void gemm_core(const u16* sw, const short8* afr,
                                          int m, int qd, int arow,
                                          const float* __restrict__ dinv,
                                          u16* __restrict__ B, int N) {
  const bool ok = (arow < N);
  const float dr = ok ? dinv[arow] : 0.f;
#pragma unroll
  for (int c = 0; c < 8; ++c) {
    f32x4 acc = {0.f, 0.f, 0.f, 0.f};
    const int n = c * 16 + m;
#pragma unroll
    for (int s = 0; s < 4; ++s) {
      short8 bfr = *(const short8*)(sw + n * 136 + 32 * s + 8 * qd);
      acc = __builtin_amdgcn_mfma_f32_16x16x32_bf16(bfr, afr[s], acc, 0, 0, 0);
    }
    if (ok) {
      u16x4 o;
#pragma unroll
      for (int r = 0; r < 4; ++r) o[r] = f2bf(dr * acc[r]);
      *(u16x4*)(B + (size_t)arow * HD + c * 16 + qd * 4) = o;
    }
  }
}

__device__ __forceinline__ void stage_w(const u16* __restrict__ Wt, u16* sw, int t) {
  const uint32_t* src = (const uint32_t*)Wt;
  uint32_t* dst = (uint32_t*)sw;
#pragma unroll
  for (int k = 0; k < 32; ++k) {
    int q = t + k * 256;
    int r = q >> 6;
    int u = q & 63;
    dst[r * 68 + u] = src[r * 64 + u];
  }
}

// layer-0 GEMM with fused h0 construction: reads x[N,64] fp32 directly.
__global__ __launch_bounds__(256)
void gemm0_k(const float* __restrict__ x, const u16* __restrict__ Wt,
             const float* __restrict__ dinv, u16* __restrict__ B, int N) {
  __shared__ u16 sw[128 * 136];
  const int t = threadIdx.x;
  stage_w(Wt, sw, t);
  __syncthreads();
  const int w = t >> 6;
  const int lane = t & 63;
  const int m = lane & 15;
  const int qd = lane >> 4;
  const int arow = blockIdx.x * 64 + w * 16 + m;
  short8 afr[4];
  if (arow < N) {
    const float* xp = x + (size_t)arow * 64;
    float v0[8], v1[8];
    *(float4*)&v0[0] = *(const float4*)(xp + 8 * qd);
    *(float4*)&v0[4] = *(const float4*)(xp + 8 * qd + 4);
    *(float4*)&v1[0] = *(const float4*)(xp + 32 + 8 * qd);
    *(float4*)&v1[4] = *(const float4*)(xp + 32 + 8 * qd + 4);
#pragma unroll
    for (int j = 0; j < 8; ++j) {
      bool n0 = isnan(v0[j]), n1 = isnan(v1[j]);
      afr[0][j] = (short)f2bf(n0 ? 0.f : v0[j]);
      afr[1][j] = (short)f2bf(n1 ? 0.f : v1[j]);
      afr[2][j] = (short)(n0 ? 0x3F80 : 0);
      afr[3][j] = (short)(n1 ? 0x3F80 : 0);
    }
  } else {
    short8 z = {0, 0, 0, 0, 0, 0, 0, 0};
#pragma unroll
    for (int s = 0; s < 4; ++s) afr[s] = z;
  }
  gemm_core(sw, afr, m, qd, arow, dinv, B, N);
}

// generic GEMM: B = dinv-scaled rows of (A @ W), A bf16
__global__ __launch_bounds__(256)
void gemm_k(const u16* __restrict__ A, const u16* __restrict__ Wt,
            const float* __restrict__ dinv, u16* __restrict__ B, int N) {
  __shared__ u16 sw[128 * 136];
  const int t = threadIdx.x;
  stage_w(Wt, sw, t);
  __syncthreads();
  const int w = t >> 6;
  const int lane = t & 63;
  const int m = lane & 15;
  const int qd = lane >> 4;
  const int arow = blockIdx.x * 64 + w * 16 + m;
  short8 afr[4];
  if (arow < N) {
    const short8* ap = (const short8*)(A + (size_t)arow * HD);
#pragma unroll
    for (int s = 0; s < 4; ++s) afr[s] = ap[4 * s + qd];
  } else {
    short8 z = {0, 0, 0, 0, 0, 0, 0, 0};
#pragma unroll
    for (int s = 0; s < 4; ++s) afr[s] = z;
  }
  gemm_core(sw, afr, m, qd, arow, dinv, B, N);
}

// Fused: A[n] = BN?ReLU( dinv[n]*(C[n] + sum_in w*C[row]) + bias )
// C = dinv-prescaled GEMM output.  Feature-QUARTER split with XCD-pair
// affinity: quarter q (32 feats) runs only on XCD slots {2q,2q+1}
// (blockIdx&7 = XCD, round-robin heuristic m09).  Per-quarter gather
// working set = N*64B = 3.2MB < 4MB per-XCD L2 -> B-quarter stays
// L2-resident.  4 lanes/node, 16B gathers (64B/edge contiguous per group).
__global__ __launch_bounds__(256)
void aggregate_k(const int* __restrict__ offs, const int2* __restrict__ csc,
                 const u16* __restrict__ B, const float* __restrict__ dinv,
                 const float* __restrict__ bias, const float* __restrict__ gamma,
                 const float* __restrict__ beta, const float* __restrict__ mean,
                 const float* __restrict__ var, int do_bn,
                 u16* __restrict__ A, int N, int nbq) {
  int b = blockIdx.x;
  int slot = b & 7;
  int qtr = slot >> 1;                    // feature quarter 0..3
  int j = ((b >> 3) << 1) + (slot & 1);   // node-block index within quarter
  if (j >= nbq) return;
  int n = j * 64 + (threadIdx.x >> 2);
  if (n >= N) return;
  int f8 = ((threadIdx.x & 3) << 3) + (qtr << 5);
  float acc[8];
  short8 bu = *(const short8*)(B + (size_t)n * HD + f8);
#pragma unroll
  for (int u = 0; u < 8; ++u) acc[u] = bf2f((u16)bu[u]);   // self term C[n]

  int p = offs[n], pe = offs[n + 1];
  for (; p + 7 < pe; p += 8) {
    int2 e[8];
    short8 h[8];
#pragma unroll
    for (int u = 0; u < 8; ++u) e[u] = csc[p + u];
#pragma unroll
    for (int u = 0; u < 8; ++u) h[u] = *(const short8*)(B + (size_t)e[u].x * HD + f8);
#pragma unroll
    for (int u = 0; u < 8; ++u) {
      float w = __int_as_float(e[u].y);
#pragma unroll
      for (int q = 0; q < 8; ++q) acc[q] += w * bf2f((u16)h[u][q]);
    }
  }
  for (; p + 1 < pe; p += 2) {
    int2 e0 = csc[p], e1 = csc[p + 1];
    short8 h0 = *(const short8*)(B + (size_t)e0.x * HD + f8);
    short8 h1 = *(const short8*)(B + (size_t)e1.x * HD + f8);
    float w0 = __int_as_float(e0.y), w1 = __int_as_float(e1.y);
#pragma unroll
    for (int q = 0; q < 8; ++q)
      acc[q] += w0 * bf2f((u16)h0[q]) + w1 * bf2f((u16)h1[q]);
  }
  if (p < pe) {
    int2 e0 = csc[p];
    float w0 = __int_as_float(e0.y);
    short8 h0 = *(const short8*)(B + (size_t)e0.x * HD + f8);
#pragma unroll
    for (int q = 0; q < 8; ++q) acc[q] += w0 * bf2f((u16)h0[q]);
  }
  float dn = dinv[n];
#pragma unroll
  for (int q = 0; q < 8; ++q) acc[q] = dn * acc[q] + bias[f8 + q];
  if (do_bn) {
#pragma unroll
    for (int q = 0; q < 8; ++q) {
      float s = gamma[f8 + q] * rsqrtf(var[f8 + q] + 1e-5f);
      float v = (acc[q] - mean[f8 + q]) * s + beta[f8 + q];
      acc[q] = v > 0.f ? v : 0.f;
    }
  }
  short8 o;
#pragma unroll
  for (int q = 0; q < 8; ++q) o[q] = (short)f2bf(acc[q]);
  *(short8*)(A + (size_t)n * HD + f8) = o;
}

__device__ __forceinline__ int seg_lower_bound(const int* b32, int N, int b) {
  int lo = 0, hi = N;
  while (lo < hi) {
    int mid = (lo + hi) >> 1;
    if (b32[mid] < b) lo = mid + 1; else hi = mid;
  }
  return lo;
}

// two-stage mean pool, stage 1 (bf16 input); atomic-free: each (graph,chunk)
// block writes its partial to part[(b*PCH+chunk)*HD + j] (plain stores).
__global__ __launch_bounds__(128)
void pool1_k(const u16* __restrict__ A, const int* __restrict__ b32,
             float* __restrict__ part, int N) {
  __shared__ int sb[2];
  int b = blockIdx.y;
  if (threadIdx.x < 2) sb[threadIdx.x] = seg_lower_bound(b32, N, b + threadIdx.x);
  __syncthreads();
  int s = sb[0], e = sb[1];
  int j = threadIdx.x;
  float a0 = 0.f, a1 = 0.f, a2 = 0.f, a3 = 0.f;
  int len = e - s;
  if (len > 0) {
    int nch = gridDim.x;
    int ch = (len + nch - 1) / nch;
    int lo = s + blockIdx.x * ch;
    int hi = lo + ch; if (hi > e) hi = e;
    int n = lo;
    for (; n + 3 < hi; n += 4) {
      a0 += bf2f(A[(size_t)(n + 0) * HD + j]);
      a1 += bf2f(A[(size_t)(n + 1) * HD + j]);
      a2 += bf2f(A[(size_t)(n + 2) * HD + j]);
      a3 += bf2f(A[(size_t)(n + 3) * HD + j]);
    }
    for (; n < hi; ++n) a0 += bf2f(A[(size_t)n * HD + j]);
  }
  part[((size_t)b * PCH + blockIdx.x) * HD + j] = (a0 + a1) + (a2 + a3);
}

// out = gelu((mean)@mW1+mb1) @ mW2 + mb2 ; mean from PCH partials
__global__ __launch_bounds__(128)
void mlp_k(const float* __restrict__ part, const int* __restrict__ b32,
           const float* __restrict__ mW1, const float* __restrict__ mb1,
           const float* __restrict__ mW2, const float* __restrict__ mb2,
           float* __restrict__ out, int N) {
  __shared__ float sg[128];
  __shared__ float st[128];
  __shared__ int sb[2];
  int b = blockIdx.x, j = threadIdx.x;
  if (j < 2) sb[j] = seg_lower_bound(b32, N, b + j);
  __syncthreads();
  int cnt = sb[1] - sb[0];
  float inv = 1.0f / (float)(cnt > 0 ? cnt : 1);
  float s0 = 0.f;
#pragma unroll
  for (int c = 0; c < PCH; ++c) s0 += part[((size_t)b * PCH + c) * HD + j];
  sg[j] = s0 * inv;
  __syncthreads();
  float s = mb1[j];
#pragma unroll 4
  for (int i = 0; i < 128; ++i) s += sg[i] * mW1[i * 128 + j];
  float ge = 0.5f * s * (1.0f + erff(s * 0.70710678118654752f));
  st[j] = ge;
  __syncthreads();
  if (j < OUTD) {
    float o = mb2[j];
#pragma unroll 4
    for (int k = 0; k < 128; ++k) o += st[k] * mW2[k * OUTD + j];
    out[b * OUTD + j] = o;
  }
}

// ---------------------------------------------------------------- launch
extern "C" void kernel_launch(void* const* d_in, const int* in_sizes, int n_in,
                              void* d_out, int out_size, void* d_ws, size_t ws_size,
                              hipStream_t stream) {
  const float* x   = (const float*)d_in[0];
  const int* ei    = (const int*)d_in[1];
  const float* ea  = (const float*)d_in[2];
  const int* bt    = (const int*)d_in[3];
  const float* W0  = (const float*)d_in[4];
  const float* b0  = (const float*)d_in[5];
  const float* W1  = (const float*)d_in[6];
  const float* b1  = (const float*)d_in[7];
  const float* W2  = (const float*)d_in[8];
  const float* b2  = (const float*)d_in[9];
  const float* bng = (const float*)d_in[10];
  const float* bnb = (const float*)d_in[11];
  const float* bnm = (const float*)d_in[12];
  const float* bnv = (const float*)d_in[13];
  const float* mW1 = (const float*)d_in[14];
  const float* mb1 = (const float*)d_in[15];
  const float* mW2 = (const float*)d_in[16];
  const float* mb2 = (const float*)d_in[17];
  float* out = (float*)d_out;

  const int N = in_sizes[0] / 64;      // 50000
  const int E = in_sizes[2];           // 800000

  char* ws = (char*)d_ws;
  size_t NB2 = (size_t)N * HD * 2;     // bf16 feature buffer
  u16* A       = (u16*)(ws);
  u16* B       = (u16*)(ws + NB2);
  char* q      = ws + 2 * NB2;
  int*   cntR  = (int*)q;              q += (size_t)NR * N * 4;
  float* part  = (float*)q;            q += (size_t)GD * PCH * HD * 4;
  u16* Wt      = (u16*)q;              q += (size_t)3 * HD * HD * 2;
  int2* csc    = (int2*)q;             q += (size_t)E * 8;
  float* dinv  = (float*)q;            q += (size_t)N * 4;
  int*   cursR = (int*)q;              q += (size_t)NR * N * 4;
  int*   offs  = (int*)q;              q += (size_t)(N + 2) * 4;
  int*   b32   = (int*)q;              q += (size_t)N * 4;
  int*   bsum  = (int*)q;              q += 64 * 4;

  dim3 blk(256);
  int gE  = (E + 255) / 256;
  int gN  = (N + 255) / 256;
  int nb1024 = (N + 1023) / 1024;

  hipMemsetAsync(cntR, 0, (size_t)NR * N * 4, stream);
  count_k<<<gE, blk, 0, stream>>>(ei, bt, b32, cntR, E, N);
  scan1_k<<<nb1024, 1024, 0, stream>>>(cntR, offs, bsum, N, N);
  scan3curs_k<<<gN, blk, 0, stream>>>(offs, bsum, cntR, cursR, N, E, N, nb1024);
  fill2_k<<<gE, blk, 0, stream>>>(ei, ea, cursR, csc, E, N);
  deg_convw_k<<<gN, blk, 0, stream>>>(offs, csc, dinv, W0, W1, W2, Wt, N);

  int gGemm = (N + 63) / 64;
  // aggregate grid: nbq node-blocks per quarter (64 nodes/block), 2 XCD
  // slots per quarter, interleaved via blockIdx&7
  int nbq  = (N + 63) / 64;
  int gAgg = ((nbq + 1) / 2) * 8;

  // layer 0 (h0 construction fused into the GEMM A-fragment load)
  gemm0_k<<<gGemm, 256, 0, stream>>>(x, Wt, dinv, B, N);
  aggregate_k<<<gAgg, blk, 0, stream>>>(offs, csc, B, dinv, b0,
                                        bng, bnb, bnm, bnv, 1, A, N, nbq);
  // layer 1
  gemm_k<<<gGemm, 256, 0, stream>>>(A, Wt + HD * HD, dinv, B, N);
  aggregate_k<<<gAgg, blk, 0, stream>>>(offs, csc, B, dinv, b1,
                                        bng, bnb, bnm, bnv, 1, A, N, nbq);
  // layer 2 (no bn/relu)
  gemm_k<<<gGemm, 256, 0, stream>>>(A, Wt + 2 * HD * HD, dinv, B, N);
  aggregate_k<<<gAgg, blk, 0, stream>>>(offs, csc, B, dinv, b2,
                                        bng, bnb, bnm, bnv, 0, A, N, nbq);

  dim3 pgrid(PCH, GD);
  pool1_k<<<pgrid, 128, 0, stream>>>(A, b32, part, N);
  mlp_k<<<GD, 128, 0, stream>>>(part, b32, mW1, mb1, mW2, mb2, out, N);
}

// Round 5
// 309.983 us; speedup vs baseline: 1.2792x; 1.2792x over previous
//
#include <hip/hip_runtime.h>
#include <hip/hip_bf16.h>
#include <stdint.h>

#define HD 128
#define GD 64
#define OUTD 16
#define PCH 32  // pool chunks per graph

typedef unsigned short u16;
typedef unsigned int u32;
typedef __attribute__((ext_vector_type(8))) short short8;
typedef __attribute__((ext_vector_type(4))) float f32x4;
typedef __attribute__((ext_vector_type(4))) unsigned short u16x4;

__device__ __forceinline__ float bf2f(u16 u) {
  union { uint32_t i; float f; } v; v.i = ((uint32_t)u) << 16; return v.f;
}
__device__ __forceinline__ u16 f2bf(float f) {
  union { __hip_bfloat16 h; u16 u; } v; v.h = __float2bfloat16(f); return v.u;
}

// exclusive scan of 256 per-thread values via LDS (Hillis-Steele).
// s is a 256-entry scratch; returns exclusive prefix; *total = sum of all.
__device__ __forceinline__ u32 excl_scan256(u32 v, u32* s, int t, u32* total) {
  s[t] = v;
  __syncthreads();
#pragma unroll
  for (int off = 1; off < 256; off <<= 1) {
    u32 x = (t >= off) ? s[t - off] : 0u;
    __syncthreads();
    s[t] += x;
    __syncthreads();
  }
  u32 incl = s[t];
  u32 tot = s[255];
  __syncthreads();
  *total = tot;
  return incl - v;
}

__device__ __forceinline__ int detect_is64(const int* ei) {
  int all0 = 1;
  for (int k = 1; k < 128; k += 2) all0 &= (ei[k] == 0);
  return all0;
}

// K1: per-block LDS histogram over col-buckets (col>>8); no global atomics.
// Also converts batch to int32.
__global__ __launch_bounds__(256)
void hist_k(const int* __restrict__ ei, const int* __restrict__ bt,
            int* __restrict__ b32, int* __restrict__ Hist, int E, int N) {
  __shared__ int h[256];
  __shared__ int s_is64;
  h[threadIdx.x] = 0;
  if (threadIdx.x == 0) s_is64 = detect_is64(ei);
  __syncthreads();
  int is64 = s_is64;
  int i = blockIdx.x * 256 + threadIdx.x;
  if (i < E) {
    int c = is64 ? ei[2 * (E + i)] : ei[E + i];
    c = (c < 0) ? 0 : (c >= N ? N - 1 : c);
    atomicAdd(&h[c >> 8], 1);              // LDS atomic
  }
  if (i < N) {
    int v = is64 ? bt[2 * i] : bt[i];
    b32[i] = (v < 0) ? 0 : (v >= GD ? GD - 1 : v);
  }
  __syncthreads();
  Hist[(size_t)blockIdx.x * 256 + threadIdx.x] = h[threadIdx.x];
}

// K2: for bucket b = blockIdx, exclusive-scan Hist[*][b] across blocks.
// Off[blk][b] = # of bucket-b edges in blocks < blk.  totals[b] = bucket size.
__global__ __launch_bounds__(256)
void scan_k(const int* __restrict__ Hist, int* __restrict__ Off,
            int* __restrict__ totals, int nblk) {
  __shared__ u32 s[256];
  int b = blockIdx.x, t = threadIdx.x;
  int chunk = (nblk + 255) >> 8;
  int i0 = t * chunk;
  int i1 = i0 + chunk; if (i1 > nblk) i1 = nblk;
  u32 part = 0;
  for (int i = i0; i < i1; ++i) part += (u32)Hist[(size_t)i * 256 + b];
  u32 tot;
  u32 run = excl_scan256(part, s, t, &tot);
  for (int i = i0; i < i1; ++i) {
    u32 h = (u32)Hist[(size_t)i * 256 + b];
    Off[(size_t)i * 256 + b] = (int)run;
    run += h;
  }
  if (t == 0) totals[b] = (int)tot;
}

// K2b: bucketBase = exclusive scan of totals; offs[N] = E.
__global__ __launch_bounds__(256)
void base_k(const int* __restrict__ totals, int* __restrict__ bucketBase,
            int* __restrict__ offs, int nbuk, int N, int E) {
  __shared__ u32 s[256];
  int t = threadIdx.x;
  u32 v = (t < nbuk) ? (u32)totals[t] : 0u;
  u32 tot;
  u32 excl = excl_scan256(v, s, t, &tot);
  bucketBase[t] = (int)excl;              // t >= nbuk gets E (harmless)
  if (t == 0) offs[N] = E;
}

// K3: scatter edges into bucket-partitioned tmp; position from LDS cursor
// (no global atomics).  tmp record: {colLow<<16 | row, bits(|w|)} (row<2^16).
__global__ __launch_bounds__(256)
void scat_k(const int* __restrict__ ei, const float* __restrict__ ea,
            const int* __restrict__ bucketBase, const int* __restrict__ Off,
            int2* __restrict__ tmp, int E, int N, int nbuk) {
  __shared__ u32 cur[256];
  __shared__ int s_is64;
  int t = threadIdx.x;
  if (t == 0) s_is64 = detect_is64(ei);
  cur[t] = (t < nbuk)
         ? (u32)(bucketBase[t] + Off[(size_t)blockIdx.x * 256 + t]) : 0u;
  __syncthreads();
  int is64 = s_is64;
  int i = blockIdx.x * 256 + t;
  if (i >= E) return;
  int r = is64 ? ei[2 * i] : ei[i];
  int c = is64 ? ei[2 * (E + i)] : ei[E + i];
  r = (r < 0) ? 0 : (r >= N ? N - 1 : r);
  c = (c < 0) ? 0 : (c >= N ? N - 1 : c);
  float a = ea[i];
  float w = isnan(a) ? 0.f : fabsf(a);
  u32 pos = atomicAdd(&cur[c >> 8], 1u);  // LDS atomic
  tmp[pos] = make_int2((int)(((u32)(c & 255) << 16) | (u32)r), __float_as_int(w));
}

// K4: per-bucket column sort: LDS count over 256 cols -> scan -> offs write ->
// LDS-cursor scatter into final csc.  Skew-safe (strided global loop).
__global__ __launch_bounds__(256)
void sort_k(const int2* __restrict__ tmp, const int* __restrict__ bucketBase,
            int2* __restrict__ csc, int* __restrict__ offs, int N) {
  __shared__ u32 cnt[256];
  __shared__ u32 s[256];
  __shared__ u32 cur[256];
  int b = blockIdx.x, t = threadIdx.x;
  int s0 = bucketBase[b], s1 = bucketBase[b + 1];
  cnt[t] = 0;
  __syncthreads();
  for (int p = s0 + t; p < s1; p += 256) {
    u32 rc = (u32)tmp[p].x;
    atomicAdd(&cnt[rc >> 16], 1u);
  }
  __syncthreads();
  u32 tot;
  u32 excl = excl_scan256(cnt[t], s, t, &tot);
  u32 st = (u32)s0 + excl;
  int col = (b << 8) + t;
  if (col < N) offs[col] = (int)st;
  cur[t] = st;
  __syncthreads();
  for (int p = s0 + t; p < s1; p += 256) {
    int2 r = tmp[p];
    u32 rc = (u32)r.x;
    u32 pos = atomicAdd(&cur[rc >> 16], 1u);
    csc[pos] = make_int2((int)(rc & 0xFFFFu), r.y);
  }
}

// merged: dinv[n] = rsqrt(sum of in-weights + 1)  AND
// transpose+convert all 3 weights: Wt[l][n][k] = bf16(W_l[k][n])
__global__ void deg_convw_k(const int* __restrict__ offs, const int2* __restrict__ csc,
                            float* __restrict__ dinv,
                            const float* __restrict__ W0, const float* __restrict__ W1,
                            const float* __restrict__ W2, u16* __restrict__ Wt, int N) {
  int i = blockIdx.x * 256 + threadIdx.x;
  if (i < 3 * HD * HD) {
    int l = i / (HD * HD);
    int r = i - l * (HD * HD);
    int n = r >> 7, k = r & 127;
    const float* W = (l == 0) ? W0 : (l == 1) ? W1 : W2;
    Wt[i] = f2bf(W[k * HD + n]);
  }
  if (i < N) {
    int p = offs[i], pe = offs[i + 1];
    float s = 0.f;
    for (; p < pe; ++p) s += __int_as_float(csc[p].y);
    dinv[i] = rsqrtf(s + 1.0f);
  }
}

// ---- shared MFMA core (operands swapped: mfma(W_frag, A_frag)).
// Lane owns x-row arow and 4 consecutive output columns n = c*16 + qd*4 + r.
// Epilogue: one dinv scalar, 8B packed stores.
__device__ __forceinline__ void gemm_core(const u16* sw, const short8* afr,
                                          int m, int qd, int arow,
                                          const float* __restrict__ dinv,
                                          u16* __restrict__ B, int N) {
  const bool ok = (arow < N);
  const float dr = ok ? dinv[arow] : 0.f;
#pragma unroll
  for (int c = 0; c < 8; ++c) {
    f32x4 acc = {0.f, 0.f, 0.f, 0.f};
    const int n = c * 16 + m;
#pragma unroll
    for (int s = 0; s < 4; ++s) {
      short8 bfr = *(const short8*)(sw + n * 136 + 32 * s + 8 * qd);
      acc = __builtin_amdgcn_mfma_f32_16x16x32_bf16(bfr, afr[s], acc, 0, 0, 0);
    }
    if (ok) {
      u16x4 o;
#pragma unroll
      for (int r = 0; r < 4; ++r) o[r] = f2bf(dr * acc[r]);
      *(u16x4*)(B + (size_t)arow * HD + c * 16 + qd * 4) = o;
    }
  }
}

__device__ __forceinline__ void stage_w(const u16* __restrict__ Wt, u16* sw, int t) {
  const uint32_t* src = (const uint32_t*)Wt;
  uint32_t* dst = (uint32_t*)sw;
#pragma unroll
  for (int k = 0; k < 32; ++k) {
    int q = t + k * 256;
    int r = q >> 6;
    int u = q & 63;
    dst[r * 68 + u] = src[r * 64 + u];
  }
}

// layer-0 GEMM with fused h0 construction: reads x[N,64] fp32 directly.
__global__ __launch_bounds__(256)
void gemm0_k(const float* __restrict__ x, const u16* __restrict__ Wt,
             const float* __restrict__ dinv, u16* __restrict__ B, int N) {
  __shared__ u16 sw[128 * 136];
  const int t = threadIdx.x;
  stage_w(Wt, sw, t);
  __syncthreads();
  const int w = t >> 6;
  const int lane = t & 63;
  const int m = lane & 15;
  const int qd = lane >> 4;
  const int arow = blockIdx.x * 64 + w * 16 + m;
  short8 afr[4];
  if (arow < N) {
    const float* xp = x + (size_t)arow * 64;
    float v0[8], v1[8];
    *(float4*)&v0[0] = *(const float4*)(xp + 8 * qd);
    *(float4*)&v0[4] = *(const float4*)(xp + 8 * qd + 4);
    *(float4*)&v1[0] = *(const float4*)(xp + 32 + 8 * qd);
    *(float4*)&v1[4] = *(const float4*)(xp + 32 + 8 * qd + 4);
#pragma unroll
    for (int j = 0; j < 8; ++j) {
      bool n0 = isnan(v0[j]), n1 = isnan(v1[j]);
      afr[0][j] = (short)f2bf(n0 ? 0.f : v0[j]);
      afr[1][j] = (short)f2bf(n1 ? 0.f : v1[j]);
      afr[2][j] = (short)(n0 ? 0x3F80 : 0);
      afr[3][j] = (short)(n1 ? 0x3F80 : 0);
    }
  } else {
    short8 z = {0, 0, 0, 0, 0, 0, 0, 0};
#pragma unroll
    for (int s = 0; s < 4; ++s) afr[s] = z;
  }
  gemm_core(sw, afr, m, qd, arow, dinv, B, N);
}

// generic GEMM: B = dinv-scaled rows of (A @ W), A bf16
__global__ __launch_bounds__(256)
void gemm_k(const u16* __restrict__ A, const u16* __restrict__ Wt,
            const float* __restrict__ dinv, u16* __restrict__ B, int N) {
  __shared__ u16 sw[128 * 136];
  const int t = threadIdx.x;
  stage_w(Wt, sw, t);
  __syncthreads();
  const int w = t >> 6;
  const int lane = t & 63;
  const int m = lane & 15;
  const int qd = lane >> 4;
  const int arow = blockIdx.x * 64 + w * 16 + m;
  short8 afr[4];
  if (arow < N) {
    const short8* ap = (const short8*)(A + (size_t)arow * HD);
#pragma unroll
    for (int s = 0; s < 4; ++s) afr[s] = ap[4 * s + qd];
  } else {
    short8 z = {0, 0, 0, 0, 0, 0, 0, 0};
#pragma unroll
    for (int s = 0; s < 4; ++s) afr[s] = z;
  }
  gemm_core(sw, afr, m, qd, arow, dinv, B, N);
}

// Fused: A[n] = BN?ReLU( dinv[n]*(C[n] + sum_in w*C[row]) + bias )
// Feature-HALF split with XCD affinity (round-3 proven): half 0 -> XCD slots
// 0-3, half 1 -> slots 4-7 via blockIdx&7 round-robin.  8 lanes/node, 16B
// gathers (128B/edge per half = one full line).
__global__ __launch_bounds__(256)
void aggregate_k(const int* __restrict__ offs, const int2* __restrict__ csc,
                 const u16* __restrict__ B, const float* __restrict__ dinv,
                 const float* __restrict__ bias, const float* __restrict__ gamma,
                 const float* __restrict__ beta, const float* __restrict__ mean,
                 const float* __restrict__ var, int do_bn,
                 u16* __restrict__ A, int N, int nbh) {
  int b = blockIdx.x;
  int half = (b >> 2) & 1;
  int j = (b & 3) | ((b >> 3) << 2);    // node-block index within half
  if (j >= nbh) return;
  int n = j * 32 + (threadIdx.x >> 3);
  if (n >= N) return;
  int f8 = ((threadIdx.x & 7) << 3) + (half << 6);
  float acc[8];
  short8 bu = *(const short8*)(B + (size_t)n * HD + f8);
#pragma unroll
  for (int u = 0; u < 8; ++u) acc[u] = bf2f((u16)bu[u]);   // self term C[n]

  int p = offs[n], pe = offs[n + 1];
  for (; p + 7 < pe; p += 8) {
    int2 e[8];
    short8 h[8];
#pragma unroll
    for (int u = 0; u < 8; ++u) e[u] = csc[p + u];
#pragma unroll
    for (int u = 0; u < 8; ++u) h[u] = *(const short8*)(B + (size_t)e[u].x * HD + f8);
#pragma unroll
    for (int u = 0; u < 8; ++u) {
      float w = __int_as_float(e[u].y);
#pragma unroll
      for (int q = 0; q < 8; ++q) acc[q] += w * bf2f((u16)h[u][q]);
    }
  }
  for (; p + 1 < pe; p += 2) {
    int2 e0 = csc[p], e1 = csc[p + 1];
    short8 h0 = *(const short8*)(B + (size_t)e0.x * HD + f8);
    short8 h1 = *(const short8*)(B + (size_t)e1.x * HD + f8);
    float w0 = __int_as_float(e0.y), w1 = __int_as_float(e1.y);
#pragma unroll
    for (int q = 0; q < 8; ++q)
      acc[q] += w0 * bf2f((u16)h0[q]) + w1 * bf2f((u16)h1[q]);
  }
  if (p < pe) {
    int2 e0 = csc[p];
    float w0 = __int_as_float(e0.y);
    short8 h0 = *(const short8*)(B + (size_t)e0.x * HD + f8);
#pragma unroll
    for (int q = 0; q < 8; ++q) acc[q] += w0 * bf2f((u16)h0[q]);
  }
  float dn = dinv[n];
#pragma unroll
  for (int q = 0; q < 8; ++q) acc[q] = dn * acc[q] + bias[f8 + q];
  if (do_bn) {
#pragma unroll
    for (int q = 0; q < 8; ++q) {
      float s = gamma[f8 + q] * rsqrtf(var[f8 + q] + 1e-5f);
      float v = (acc[q] - mean[f8 + q]) * s + beta[f8 + q];
      acc[q] = v > 0.f ? v : 0.f;
    }
  }
  short8 o;
#pragma unroll
  for (int q = 0; q < 8; ++q) o[q] = (short)f2bf(acc[q]);
  *(short8*)(A + (size_t)n * HD + f8) = o;
}

__device__ __forceinline__ int seg_lower_bound(const int* b32, int N, int b) {
  int lo = 0, hi = N;
  while (lo < hi) {
    int mid = (lo + hi) >> 1;
    if (b32[mid] < b) lo = mid + 1; else hi = mid;
  }
  return lo;
}

// two-stage mean pool, stage 1 (bf16 input); atomic-free partials.
__global__ __launch_bounds__(128)
void pool1_k(const u16* __restrict__ A, const int* __restrict__ b32,
             float* __restrict__ part, int N) {
  __shared__ int sb[2];
  int b = blockIdx.y;
  if (threadIdx.x < 2) sb[threadIdx.x] = seg_lower_bound(b32, N, b + threadIdx.x);
  __syncthreads();
  int s = sb[0], e = sb[1];
  int j = threadIdx.x;
  float a0 = 0.f, a1 = 0.f, a2 = 0.f, a3 = 0.f;
  int len = e - s;
  if (len > 0) {
    int nch = gridDim.x;
    int ch = (len + nch - 1) / nch;
    int lo = s + blockIdx.x * ch;
    int hi = lo + ch; if (hi > e) hi = e;
    int n = lo;
    for (; n + 3 < hi; n += 4) {
      a0 += bf2f(A[(size_t)(n + 0) * HD + j]);
      a1 += bf2f(A[(size_t)(n + 1) * HD + j]);
      a2 += bf2f(A[(size_t)(n + 2) * HD + j]);
      a3 += bf2f(A[(size_t)(n + 3) * HD + j]);
    }
    for (; n < hi; ++n) a0 += bf2f(A[(size_t)n * HD + j]);
  }
  part[((size_t)b * PCH + blockIdx.x) * HD + j] = (a0 + a1) + (a2 + a3);
}

// out = gelu((mean)@mW1+mb1) @ mW2 + mb2 ; mean from PCH partials
__global__ __launch_bounds__(128)
void mlp_k(const float* __restrict__ part, const int* __restrict__ b32,
           const float* __restrict__ mW1, const float* __restrict__ mb1,
           const float* __restrict__ mW2, const float* __restrict__ mb2,
           float* __restrict__ out, int N) {
  __shared__ float sg[128];
  __shared__ float st[128];
  __shared__ int sb[2];
  int b = blockIdx.x, j = threadIdx.x;
  if (j < 2) sb[j] = seg_lower_bound(b32, N, b + j);
  __syncthreads();
  int cnt = sb[1] - sb[0];
  float inv = 1.0f / (float)(cnt > 0 ? cnt : 1);
  float s0 = 0.f;
#pragma unroll
  for (int c = 0; c < PCH; ++c) s0 += part[((size_t)b * PCH + c) * HD + j];
  sg[j] = s0 * inv;
  __syncthreads();
  float s = mb1[j];
#pragma unroll 4
  for (int i = 0; i < 128; ++i) s += sg[i] * mW1[i * 128 + j];
  float ge = 0.5f * s * (1.0f + erff(s * 0.70710678118654752f));
  st[j] = ge;
  __syncthreads();
  if (j < OUTD) {
    float o = mb2[j];
#pragma unroll 4
    for (int k = 0; k < 128; ++k) o += st[k] * mW2[k * OUTD + j];
    out[b * OUTD + j] = o;
  }
}

// ---------------------------------------------------------------- launch
extern "C" void kernel_launch(void* const* d_in, const int* in_sizes, int n_in,
                              void* d_out, int out_size, void* d_ws, size_t ws_size,
                              hipStream_t stream) {
  const float* x   = (const float*)d_in[0];
  const int* ei    = (const int*)d_in[1];
  const float* ea  = (const float*)d_in[2];
  const int* bt    = (const int*)d_in[3];
  const float* W0  = (const float*)d_in[4];
  const float* b0  = (const float*)d_in[5];
  const float* W1  = (const float*)d_in[6];
  const float* b1  = (const float*)d_in[7];
  const float* W2  = (const float*)d_in[8];
  const float* b2  = (const float*)d_in[9];
  const float* bng = (const float*)d_in[10];
  const float* bnb = (const float*)d_in[11];
  const float* bnm = (const float*)d_in[12];
  const float* bnv = (const float*)d_in[13];
  const float* mW1 = (const float*)d_in[14];
  const float* mb1 = (const float*)d_in[15];
  const float* mW2 = (const float*)d_in[16];
  const float* mb2 = (const float*)d_in[17];
  float* out = (float*)d_out;

  const int N = in_sizes[0] / 64;      // 50000  (rows fit in 16 bits)
  const int E = in_sizes[2];           // 800000

  char* ws = (char*)d_ws;
  size_t NB2 = (size_t)N * HD * 2;     // bf16 feature buffer
  u16* A       = (u16*)(ws);
  u16* B       = (u16*)(ws + NB2);
  char* q      = ws + 2 * NB2;
  float* part  = (float*)q;            q += (size_t)GD * PCH * HD * 4;
  u16* Wt      = (u16*)q;              q += (size_t)3 * HD * HD * 2;
  int2* csc    = (int2*)q;             q += (size_t)E * 8;
  int2* tmp    = (int2*)q;             q += (size_t)E * 8;
  int gE  = (E + 255) / 256;
  int*   Hist  = (int*)q;              q += (size_t)gE * 256 * 4;
  int*   Off   = (int*)q;              q += (size_t)gE * 256 * 4;
  int*   totals= (int*)q;              q += 256 * 4;
  int*   bBase = (int*)q;              q += 260 * 4;
  float* dinv  = (float*)q;            q += (size_t)N * 4;
  int*   offs  = (int*)q;              q += (size_t)(N + 2) * 4;
  int*   b32   = (int*)q;              q += (size_t)N * 4;

  dim3 blk(256);
  int gN   = (N + 255) / 256;
  int nbuk = gN;                       // col buckets (col>>8)

  hist_k<<<gE, blk, 0, stream>>>(ei, bt, b32, Hist, E, N);
  scan_k<<<nbuk, blk, 0, stream>>>(Hist, Off, totals, gE);
  base_k<<<1, blk, 0, stream>>>(totals, bBase, offs, nbuk, N, E);
  scat_k<<<gE, blk, 0, stream>>>(ei, ea, bBase, Off, tmp, E, N, nbuk);
  sort_k<<<nbuk, blk, 0, stream>>>(tmp, bBase, csc, offs, N);
  deg_convw_k<<<gN, blk, 0, stream>>>(offs, csc, dinv, W0, W1, W2, Wt, N);

  int gGemm = (N + 63) / 64;
  int nbh  = (N + 31) / 32;
  int nb4  = (nbh + 3) / 4;
  int gAgg = nb4 * 8;

  // layer 0 (h0 construction fused into the GEMM A-fragment load)
  gemm0_k<<<gGemm, 256, 0, stream>>>(x, Wt, dinv, B, N);
  aggregate_k<<<gAgg, blk, 0, stream>>>(offs, csc, B, dinv, b0,
                                        bng, bnb, bnm, bnv, 1, A, N, nbh);
  // layer 1
  gemm_k<<<gGemm, 256, 0, stream>>>(A, Wt + HD * HD, dinv, B, N);
  aggregate_k<<<gAgg, blk, 0, stream>>>(offs, csc, B, dinv, b1,
                                        bng, bnb, bnm, bnv, 1, A, N, nbh);
  // layer 2 (no bn/relu)
  gemm_k<<<gGemm, 256, 0, stream>>>(A, Wt + 2 * HD * HD, dinv, B, N);
  aggregate_k<<<gAgg, blk, 0, stream>>>(offs, csc, B, dinv, b2,
                                        bng, bnb, bnm, bnv, 0, A, N, nbh);

  dim3 pgrid(PCH, GD);
  pool1_k<<<pgrid, 128, 0, stream>>>(A, b32, part, N);
  mlp_k<<<GD, 128, 0, stream>>>(part, b32, mW1, mb1, mW2, mb2, out, N);
}